// Round 3
// baseline (318.592 us; speedup 1.0000x reference)
//
#include <hip/hip_runtime.h>
#include <hip/hip_bf16.h>

// GLM flash attention fwd: b=2, s=2048, nh=16, hs=64, fp32 in/out,
// bf16 MFMA internal compute (threshold is 2% of max|ref| -> ample headroom).
// allowed(i,j) = (j <= i) || (j < glm_mask[b]); softmax scale 1/8.
// One wave per 16-row Q tile; K/V walked in 32-col chunks, online softmax.
// The 4 waves of a block share (b, qt) -> identical trip counts ->
// __syncthreads() legally brackets the P LDS round-trip.

typedef __attribute__((ext_vector_type(8))) __bf16 bf16x8;
typedef __attribute__((ext_vector_type(4))) float floatx4;

#define S_LEN 2048
#define NH 16
#define HS 64
#define ROW_STRIDE (NH * HS)  // 1024 elements between consecutive seq positions
#define NEG_BIG (-30000.0f)   // finite "masked" score; exp underflows cleanly

__device__ __forceinline__ bf16x8 load_cvt8(const float* p) {
    floatx4 a = *(const floatx4*)p;        // 16B aligned
    floatx4 b = *(const floatx4*)(p + 4);
    bf16x8 r;
    r[0] = (__bf16)a[0]; r[1] = (__bf16)a[1]; r[2] = (__bf16)a[2]; r[3] = (__bf16)a[3];
    r[4] = (__bf16)b[0]; r[5] = (__bf16)b[1]; r[6] = (__bf16)b[2]; r[7] = (__bf16)b[3];
    return r;
}

__global__ __launch_bounds__(256) void fa_glm_kernel(
    const float* __restrict__ q,
    const float* __restrict__ k,
    const float* __restrict__ v,
    const int* __restrict__ glm_mask,
    float* __restrict__ out)
{
    // per-wave private P staging: 16 rows x 32 cols, row stride 40 bf16 (80 B:
    // 16B-aligned rows; ds_read_b128 lands 2-way on banks = free per m136)
    __shared__ __bf16 p_lds[4][16 * 40];

    const int wave = threadIdx.x >> 6;
    const int lane = threadIdx.x & 63;
    const int col  = lane & 15;
    const int quad = lane >> 4;

    // block -> (b, qt, head-group); wave picks the head within the group
    const int b   = blockIdx.x >> 9;          // 512 blocks per batch
    const int xr  = blockIdx.x & 511;
    const int qt  = 127 - (xr >> 2);          // biggest k-range first
    const int h   = (xr & 3) * 4 + wave;
    const int q0  = qt * 16;

    const int bp   = glm_mask[b];
    const int kc   = q0 + 16;
    const int klen = (kc > bp) ? kc : bp;     // cols [0, klen) may be live

    const long base = (long)b * (S_LEN * ROW_STRIDE) + h * HS;
    const float* qb = q + base;
    const float* kb = k + base;
    const float* vb = v + base;
    float* ob = out + base;

    // Q fragments (A operand): A[m=col][kd = quad*8 + j (+32)]
    bf16x8 aq0 = load_cvt8(qb + (q0 + col) * ROW_STRIDE + quad * 8);
    bf16x8 aq1 = load_cvt8(qb + (q0 + col) * ROW_STRIDE + 32 + quad * 8);

    floatx4 o[4];   // O C-frags, feature = f*16 + col; rows = quad*4 + r
    float m[4], l[4];
#pragma unroll
    for (int r = 0; r < 4; ++r) {
        o[r] = (floatx4){0.f, 0.f, 0.f, 0.f};
        m[r] = NEG_BIG;
        l[r] = 0.f;
    }

    __bf16* pw = &p_lds[wave][0];

    for (int k0 = 0; k0 < klen; k0 += 32) {
        // K fragments (B operand): B[kd][n=col] = K[k0+col][kd]
        bf16x8 bk00 = load_cvt8(kb + (k0 + col) * ROW_STRIDE + quad * 8);
        bf16x8 bk01 = load_cvt8(kb + (k0 + col) * ROW_STRIDE + 32 + quad * 8);
        bf16x8 bk10 = load_cvt8(kb + (k0 + 16 + col) * ROW_STRIDE + quad * 8);
        bf16x8 bk11 = load_cvt8(kb + (k0 + 16 + col) * ROW_STRIDE + 32 + quad * 8);

        floatx4 z = {0.f, 0.f, 0.f, 0.f};
        floatx4 s0 = __builtin_amdgcn_mfma_f32_16x16x32_bf16(aq0, bk00, z, 0, 0, 0);
        s0 = __builtin_amdgcn_mfma_f32_16x16x32_bf16(aq1, bk01, s0, 0, 0, 0);
        floatx4 s1 = __builtin_amdgcn_mfma_f32_16x16x32_bf16(aq0, bk10, z, 0, 0, 0);
        s1 = __builtin_amdgcn_mfma_f32_16x16x32_bf16(aq1, bk11, s1, 0, 0, 0);

        const int kj0 = k0 + col;
        const int kj1 = kj0 + 16;
#pragma unroll
        for (int r = 0; r < 4; ++r) {
            const int qi = q0 + quad * 4 + r;
            float sv0 = ((kj0 <= qi) || (kj0 < bp)) ? s0[r] * 0.125f : NEG_BIG;
            float sv1 = ((kj1 <= qi) || (kj1 < bp)) ? s1[r] * 0.125f : NEG_BIG;

            // row max across the 16 lanes of the quad group (xor<16 stays in-group)
            float mt = fmaxf(sv0, sv1);
            mt = fmaxf(mt, __shfl_xor(mt, 1));
            mt = fmaxf(mt, __shfl_xor(mt, 2));
            mt = fmaxf(mt, __shfl_xor(mt, 4));
            mt = fmaxf(mt, __shfl_xor(mt, 8));

            float mnew = fmaxf(m[r], mt);
            float al = __expf(m[r] - mnew);   // first chunk: exp(~-30000) = 0
            float p0 = __expf(sv0 - mnew);    // masked: exp(<= -29000) = 0
            float p1 = __expf(sv1 - mnew);
            float rs = p0 + p1;
            rs += __shfl_xor(rs, 1);
            rs += __shfl_xor(rs, 2);
            rs += __shfl_xor(rs, 4);
            rs += __shfl_xor(rs, 8);
            l[r] = l[r] * al + rs;
            m[r] = mnew;
            o[0][r] *= al; o[1][r] *= al; o[2][r] *= al; o[3][r] *= al;

            // P (C layout) -> LDS, bf16
            __bf16* prow = pw + (quad * 4 + r) * 40;
            prow[col]      = (__bf16)p0;
            prow[16 + col] = (__bf16)p1;
        }

        __syncthreads();  // P writes visible & ordered before the A-frag read

        // P back as A operand: A[m=col][kd=quad*8+j], 16B ds_read
        bf16x8 ap = *(const bf16x8*)(pw + col * 40 + quad * 8);

        // V as B operand: B[kd=j][n=feature] -> scalar strided loads (L2-resident)
        const float* vp = vb + (k0 + quad * 8) * ROW_STRIDE + col;
#pragma unroll
        for (int f = 0; f < 4; ++f) {
            bf16x8 bv;
#pragma unroll
            for (int jj = 0; jj < 8; ++jj)
                bv[jj] = (__bf16)vp[jj * ROW_STRIDE + f * 16];
            o[f] = __builtin_amdgcn_mfma_f32_16x16x32_bf16(ap, bv, o[f], 0, 0, 0);
        }

        __syncthreads();  // keep next iteration's P writes behind this read
    }

#pragma unroll
    for (int r = 0; r < 4; ++r) {
        const float inv = (l[r] > 0.f) ? (1.0f / l[r]) : 0.f;  // NaN-proof guard
        const int row = q0 + quad * 4 + r;
#pragma unroll
        for (int f = 0; f < 4; ++f)
            ob[row * ROW_STRIDE + f * 16 + col] = o[f][r] * inv;
    }
}

extern "C" void kernel_launch(void* const* d_in, const int* in_sizes, int n_in,
                              void* d_out, int out_size, void* d_ws, size_t ws_size,
                              hipStream_t stream) {
    const float* q  = (const float*)d_in[0];
    const float* k  = (const float*)d_in[1];
    const float* v  = (const float*)d_in[2];
    const int* glm  = (const int*)d_in[3];
    float* out      = (float*)d_out;

    // 2 batches * 128 q-tiles * 4 head-groups = 1024 blocks, 4 waves each
    dim3 grid(1024), block(256);
    hipLaunchKernelGGL(fa_glm_kernel, grid, block, 0, stream, q, k, v, glm, out);
}